// Round 2
// baseline (6712.659 us; speedup 1.0000x reference)
//
#include <hip/hip_runtime.h>
#include <hip/hip_bf16.h>
#include <math.h>

// Problem constants
#define Bc 2
#define Tc 4096
#define Dc 1024
#define Hc 16
#define DKc 64
#define DVc 128
#define KDIMc 1024   // H*DK
#define VDIMc 2048   // H*DV
#define Mrows (Bc*Tc) // 8192

__device__ __forceinline__ float siluf(float x) {
    return x / (1.f + expf(-x));
}

// ---------------------------------------------------------------------------
// Generic tiled f32 GEMM: C[M,N] = A[M,K] @ B[K,N], all row-major.
// BM=BN=64, BK=16, 256 threads, 4x4 per thread.
// ---------------------------------------------------------------------------
#define GBM 64
#define GBN 64
#define GBK 16
__global__ void __launch_bounds__(256) gemm_f32(
    const float* __restrict__ A, const float* __restrict__ B,
    float* __restrict__ C, int M, int N, int K) {
    __shared__ float As[GBK][GBM + 4];  // transposed: As[k][m], padded
    __shared__ float Bs[GBK][GBN];
    const int tid = threadIdx.x;
    const int nbx = N / GBN;
    const int bx = blockIdx.x % nbx;
    const int by = blockIdx.x / nbx;
    const int row0 = by * GBM, col0 = bx * GBN;
    const int ty = tid >> 4, tx = tid & 15;
    const int ar = tid >> 2, ak = (tid & 3) * 4;   // A tile load coords
    const int bc = tid & 63, bk0 = (tid >> 6) * 4; // B tile load coords

    float acc[4][4];
#pragma unroll
    for (int i = 0; i < 4; i++)
#pragma unroll
        for (int j = 0; j < 4; j++) acc[i][j] = 0.f;

    for (int k0 = 0; k0 < K; k0 += GBK) {
        float4 av = *(const float4*)&A[(size_t)(row0 + ar) * K + k0 + ak];
        As[ak + 0][ar] = av.x;
        As[ak + 1][ar] = av.y;
        As[ak + 2][ar] = av.z;
        As[ak + 3][ar] = av.w;
#pragma unroll
        for (int i = 0; i < 4; i++)
            Bs[bk0 + i][bc] = B[(size_t)(k0 + bk0 + i) * N + col0 + bc];
        __syncthreads();
#pragma unroll
        for (int kk = 0; kk < GBK; kk++) {
            float a[4], b[4];
            *(float4*)a = *(const float4*)&As[kk][ty * 4];
            *(float4*)b = *(const float4*)&Bs[kk][tx * 4];
#pragma unroll
            for (int i = 0; i < 4; i++)
#pragma unroll
                for (int j = 0; j < 4; j++) acc[i][j] += a[i] * b[j];
        }
        __syncthreads();
    }
#pragma unroll
    for (int i = 0; i < 4; i++) {
        float4 v = make_float4(acc[i][0], acc[i][1], acc[i][2], acc[i][3]);
        *(float4*)&C[(size_t)(row0 + ty * 4 + i) * N + col0 + tx * 4] = v;
    }
}

// ---------------------------------------------------------------------------
// a/b projections (N=16 each) fused with softplus/sigmoid -> g, beta.
// One wave per token row; lane = h*4 + kgroup.
// ---------------------------------------------------------------------------
__global__ void __launch_bounds__(256) ab_proj(
    const float* __restrict__ x, const float* __restrict__ w_a,
    const float* __restrict__ w_b, const float* __restrict__ A_log,
    const float* __restrict__ dt_bias, float* __restrict__ g_out,
    float* __restrict__ beta_out) {
    const int row = blockIdx.x * 4 + (threadIdx.x >> 6);
    const int lane = threadIdx.x & 63;
    const int h = lane >> 2;
    const int kg = lane & 3;
    const float* xr = x + (size_t)row * Dc;
    float pa = 0.f, pb = 0.f;
    const int kbeg = kg * 256, kend = kbeg + 256;
    for (int k = kbeg; k < kend; k++) {
        float xv = xr[k];
        pa += xv * w_a[k * Hc + h];
        pb += xv * w_b[k * Hc + h];
    }
    pa += __shfl_xor(pa, 1, 64);
    pa += __shfl_xor(pa, 2, 64);
    pb += __shfl_xor(pb, 1, 64);
    pb += __shfl_xor(pb, 2, 64);
    if (kg == 0) {
        float arg = pa + dt_bias[h];
        float sp = fmaxf(arg, 0.f) + log1pf(expf(-fabsf(arg)));
        g_out[(size_t)row * Hc + h] = -expf(A_log[h]) * sp;
        beta_out[(size_t)row * Hc + h] = 2.f / (1.f + expf(-pb));
    }
}

// ---------------------------------------------------------------------------
// Save 3-row halos at 64-step chunk boundaries so the conv can run in-place.
// halo[b][chunk][j][c] = in[b][chunk*64 - 3 + j][c], chunk = 1..Tc/64-1
// ---------------------------------------------------------------------------
template <int C>
__global__ void __launch_bounds__(256) save_halo(
    const float* __restrict__ in, float* __restrict__ halo) {
    const int g = blockIdx.x * 256 + threadIdx.x;
    const int total = Bc * (Tc / 64 - 1) * 3 * C;
    if (g >= total) return;
    const int c = g % C;
    int r = g / C;
    const int j = r % 3;
    r /= 3;
    const int chunk = r % (Tc / 64 - 1) + 1;
    const int b = r / (Tc / 64 - 1);
    halo[((size_t)(b * 64 + chunk) * 3 + j) * C + c] =
        in[((size_t)b * Tc + chunk * 64 - 3 + j) * C + c];
}

// ---------------------------------------------------------------------------
// Depthwise causal conv1d (K=4) + SiLU (+ optional per-head l2norm, DK=64),
// IN PLACE. Each thread: one channel over 64 timesteps with rolling window;
// left context from the pre-saved halo buffer.
// grid = B * (T/64) * (C/256); block 256.
// ---------------------------------------------------------------------------
template <int C, bool L2N>
__global__ void __launch_bounds__(256) conv_silu_inplace(
    float* __restrict__ buf, const float* __restrict__ w,
    const float* __restrict__ halo) {
    constexpr int CB = C / 256;
    const int bidx = blockIdx.x;
    const int cb = bidx % CB;
    const int tchunk = (bidx / CB) % (Tc / 64);
    const int b = bidx / (CB * (Tc / 64));
    const int c = cb * 256 + threadIdx.x;
    const int t0 = tchunk * 64;
    const float w0 = w[c * 4 + 0], w1 = w[c * 4 + 1], w2 = w[c * 4 + 2],
                w3 = w[c * 4 + 3];
    float xm3 = 0.f, xm2 = 0.f, xm1 = 0.f;
    if (tchunk > 0) {
        const float* hp = halo + (size_t)(b * 64 + tchunk) * 3 * C + c;
        xm3 = hp[0];
        xm2 = hp[C];
        xm1 = hp[2 * C];
    }
    float* p = buf + (size_t)b * Tc * C + c;
#pragma unroll 4
    for (int i = 0; i < 64; i++) {
        float xt = p[(size_t)(t0 + i) * C];
        float y = w0 * xm3 + w1 * xm2 + w2 * xm1 + w3 * xt;
        y = siluf(y);
        if (L2N) {
            float ss = y * y;
#pragma unroll
            for (int m = 1; m < 64; m <<= 1) ss += __shfl_xor(ss, m, 64);
            y *= rsqrtf(ss + 1e-6f);
        }
        p[(size_t)(t0 + i) * C] = y;
        xm3 = xm2;
        xm2 = xm1;
        xm1 = xt;
    }
}

// ---------------------------------------------------------------------------
// Gated delta rule, sequential scan. One workgroup per (b,h); 256 threads.
// Thread (dv = tid>>1, half = tid&1) owns S[dk in half*32..+31][dv].
// ---------------------------------------------------------------------------
__global__ void __launch_bounds__(256) scan_kernel(
    const float* __restrict__ qc, const float* __restrict__ kc,
    const float* __restrict__ vc, const float* __restrict__ g,
    const float* __restrict__ beta, float* __restrict__ o) {
    const int bh = blockIdx.x;
    const int b = bh >> 4, h = bh & 15;
    const int tid = threadIdx.x;
    const int dv = tid >> 1, half = tid & 1;
    __shared__ float sk[64], sq[64], sv[128], sgb[2];
    float S[32];
#pragma unroll
    for (int j = 0; j < 32; j++) S[j] = 0.f;

    const size_t qk_base = (size_t)b * Tc * KDIMc + h * DKc;
    const size_t v_base = (size_t)b * Tc * VDIMc + h * DVc;
    const size_t gb_base = (size_t)b * Tc * Hc + h;

    // stage t=0 into registers
    float r0, r1 = 0.f;
    {
        if (tid < 64)
            r0 = kc[qk_base + tid];
        else if (tid < 128)
            r0 = qc[qk_base + (tid - 64)];
        else
            r0 = vc[v_base + (tid - 128)];
        if (tid == 0) r1 = g[gb_base];
        if (tid == 1) r1 = beta[gb_base];
    }

    for (int t = 0; t < Tc; t++) {
        __syncthreads();  // previous iteration done reading LDS
        if (tid < 64)
            sk[tid] = r0;
        else if (tid < 128)
            sq[tid - 64] = r0;
        else
            sv[tid - 128] = r0;
        if (tid < 2) sgb[tid] = r1;
        __syncthreads();
        // prefetch t+1 into registers (overlaps with compute below)
        if (t + 1 < Tc) {
            const size_t toff = (size_t)(t + 1);
            if (tid < 64)
                r0 = kc[qk_base + toff * KDIMc + tid];
            else if (tid < 128)
                r0 = qc[qk_base + toff * KDIMc + (tid - 64)];
            else
                r0 = vc[v_base + toff * VDIMc + (tid - 128)];
            if (tid == 0) r1 = g[gb_base + toff * Hc];
            if (tid == 1) r1 = beta[gb_base + toff * Hc];
        }
        const float eg = expf(sgb[0]);
        const float bt = sgb[1];
        const float vv = sv[dv];
        float kreg[32], qreg[32];
#pragma unroll
        for (int j = 0; j < 8; j++) {
            *(float4*)&kreg[j * 4] = *(const float4*)&sk[half * 32 + j * 4];
            *(float4*)&qreg[j * 4] = *(const float4*)&sq[half * 32 + j * 4];
        }
        float mem = 0.f;
#pragma unroll
        for (int j = 0; j < 32; j++) {
            S[j] *= eg;
            mem += kreg[j] * S[j];
        }
        mem += __shfl_xor(mem, 1, 64);
        const float delta = (vv - mem) * bt;
        float oacc = 0.f;
#pragma unroll
        for (int j = 0; j < 32; j++) {
            S[j] += kreg[j] * delta;
            oacc += qreg[j] * S[j];
        }
        oacc += __shfl_xor(oacc, 1, 64);
        if (half == 0)
            o[((size_t)b * Tc + t) * VDIMc + h * DVc + dv] = oacc * 0.125f;
    }
}

// ---------------------------------------------------------------------------
// Gated RMSNorm: one wave per (b,t,h) row of 128; in-place on o.
// y = o * rsqrt(mean(o^2)+eps) * norm_w * silu(g_gate)
// ---------------------------------------------------------------------------
__global__ void __launch_bounds__(256) rms_gate(
    float* __restrict__ o, const float* __restrict__ gg,
    const float* __restrict__ norm_w) {
    const int row = blockIdx.x * 4 + (threadIdx.x >> 6);
    const int lane = threadIdx.x & 63;
    const size_t base = (size_t)row * DVc;
    float2 ov = *(const float2*)&o[base + lane * 2];
    float ss = ov.x * ov.x + ov.y * ov.y;
#pragma unroll
    for (int m = 1; m < 64; m <<= 1) ss += __shfl_xor(ss, m, 64);
    const float f = rsqrtf(ss * (1.f / 128.f) + 1e-5f);
    float2 gv = *(const float2*)&gg[base + lane * 2];
    const float nw0 = norm_w[lane * 2], nw1 = norm_w[lane * 2 + 1];
    float y0 = ov.x * f * nw0 * siluf(gv.x);
    float y1 = ov.y * f * nw1 * siluf(gv.y);
    *(float2*)&o[base + lane * 2] = make_float2(y0, y1);
}

// ---------------------------------------------------------------------------
// Workspace budget (floats):
//   qb   M*KDIM  =  8388608   (q proj, conv'd in place; later aliased by gg)
//   kb   M*KDIM  =  8388608   (k proj, conv'd in place; gg tail)
//   vb   M*VDIM  = 16777216   (v proj, conv'd in place)
//   obuf M*VDIM  = 16777216   (scan output, rms in place)
//   gbuf M*H     =   131072
//   bbuf M*H     =   131072
//   halo B*64*3*VDIM = 786432
// total = 51,380,224 floats = 205.5 MB  (was 404 MB -> suspected ws overflow)
// ---------------------------------------------------------------------------
extern "C" void kernel_launch(void* const* d_in, const int* in_sizes, int n_in,
                              void* d_out, int out_size, void* d_ws,
                              size_t ws_size, hipStream_t stream) {
    const float* x = (const float*)d_in[0];
    const float* w_q = (const float*)d_in[1];
    const float* w_k = (const float*)d_in[2];
    const float* w_v = (const float*)d_in[3];
    const float* w_a = (const float*)d_in[4];
    const float* w_b = (const float*)d_in[5];
    const float* w_g = (const float*)d_in[6];
    const float* w_out = (const float*)d_in[7];
    const float* A_log = (const float*)d_in[8];
    const float* dt_bias = (const float*)d_in[9];
    const float* conv_q = (const float*)d_in[10];
    const float* conv_k = (const float*)d_in[11];
    const float* conv_v = (const float*)d_in[12];
    const float* norm_w = (const float*)d_in[13];

    float* ws = (float*)d_ws;
    const size_t M = Mrows;
    float* qb = ws;
    float* kb = qb + M * KDIMc;
    float* vb = kb + M * KDIMc;
    float* obuf = vb + M * VDIMc;
    float* gbuf = obuf + M * VDIMc;
    float* bbuf = gbuf + M * Hc;
    float* halo = bbuf + M * Hc;
    float* gg = qb;  // aliased AFTER the scan (qb+kb contiguous = M*VDIM floats)

    // 1) q/k/v projections
    gemm_f32<<<dim3((M / GBM) * (KDIMc / GBN)), 256, 0, stream>>>(
        x, w_q, qb, M, KDIMc, Dc);
    gemm_f32<<<dim3((M / GBM) * (KDIMc / GBN)), 256, 0, stream>>>(
        x, w_k, kb, M, KDIMc, Dc);
    gemm_f32<<<dim3((M / GBM) * (VDIMc / GBN)), 256, 0, stream>>>(
        x, w_v, vb, M, VDIMc, Dc);

    // 2) a/b projections fused with activation -> g, beta
    ab_proj<<<dim3(M / 4), 256, 0, stream>>>(x, w_a, w_b, A_log, dt_bias, gbuf,
                                             bbuf);

    // 3) conv + silu (+ l2norm for q,k), in place with halo save
    {
        const int nqk = Bc * (Tc / 64 - 1) * 3 * KDIMc;
        const int nv = Bc * (Tc / 64 - 1) * 3 * VDIMc;
        save_halo<KDIMc><<<dim3((nqk + 255) / 256), 256, 0, stream>>>(qb, halo);
        conv_silu_inplace<KDIMc, true>
            <<<dim3(Bc * (Tc / 64) * (KDIMc / 256)), 256, 0, stream>>>(
                qb, conv_q, halo);
        save_halo<KDIMc><<<dim3((nqk + 255) / 256), 256, 0, stream>>>(kb, halo);
        conv_silu_inplace<KDIMc, true>
            <<<dim3(Bc * (Tc / 64) * (KDIMc / 256)), 256, 0, stream>>>(
                kb, conv_k, halo);
        save_halo<VDIMc><<<dim3((nv + 255) / 256), 256, 0, stream>>>(vb, halo);
        conv_silu_inplace<VDIMc, false>
            <<<dim3(Bc * (Tc / 64) * (VDIMc / 256)), 256, 0, stream>>>(
                vb, conv_v, halo);
    }

    // 4) sequential gated delta-rule scan
    scan_kernel<<<dim3(Bc * Hc), 256, 0, stream>>>(qb, kb, vb, gbuf, bbuf,
                                                   obuf);

    // 5) gate projection (after scan so it can alias qb+kb)
    gemm_f32<<<dim3((M / GBM) * (VDIMc / GBN)), 256, 0, stream>>>(
        x, w_g, gg, M, VDIMc, Dc);

    // 6) gated RMSNorm (in place on obuf)
    rms_gate<<<dim3(M * Hc / 4), 256, 0, stream>>>(obuf, gg, norm_w);

    // 7) output projection -> d_out
    gemm_f32<<<dim3((M / GBM) * (Dc / GBN)), 256, 0, stream>>>(
        obuf, w_out, (float*)d_out, M, Dc, VDIMc);
}